// Round 5
// baseline (373.008 us; speedup 1.0000x reference)
//
#include <hip/hip_runtime.h>
#include <stdint.h>

#define C_INPUTS 41024
#define C_KEFF   40960   // last 64 cols of W are zero -> skipped exactly
#define C_L1     256
#define C_NT32   (C_KEFF / 32)                    // 1280 32-k tiles
#define WS_W_BYTES ((size_t)C_L1 * C_KEFF * 2)    // 20,971,520

typedef __attribute__((ext_vector_type(8))) short short8;
typedef __attribute__((ext_vector_type(4))) float f32x4;

__device__ __forceinline__ uint16_t bf16_rtne(float f) {
  uint32_t u = __builtin_bit_cast(uint32_t, f);
  u += 0x7fffu + ((u >> 16) & 1u);
  return (uint16_t)(u >> 16);
}

__device__ __forceinline__ short8 pack_bf16x8(float4 a, float4 b) {
  union { uint16_t h[8]; short8 v; } u;
  u.h[0] = bf16_rtne(a.x); u.h[1] = bf16_rtne(a.y);
  u.h[2] = bf16_rtne(a.z); u.h[3] = bf16_rtne(a.w);
  u.h[4] = bf16_rtne(b.x); u.h[5] = bf16_rtne(b.y);
  u.h[6] = bf16_rtne(b.z); u.h[7] = bf16_rtne(b.w);
  return u.v;
}

// ---------------------------------------------------------------------------
// Kernel 1: W [256, 41024] f32 -> bf16 workspace in FRAGMENT-MAJOR 32-k tiles.
// Tile kt: elem(kt, f, l, j) = W[16f + (l&15)][kt*32 + (l>>4)*8 + j]
// (f = 16-col frag 0..15, l = frag lane, j = 0..7). The GEMM reads each
// fragment as one contiguous 1KB wave load (lane*16B) straight to VGPRs.
// ---------------------------------------------------------------------------
__global__ __launch_bounds__(256) void k_convert_w(const float* __restrict__ W,
                                                   uint16_t* __restrict__ wsW) {
  const int kt = blockIdx.x;    // 0..1279
  const int t  = threadIdx.x;
  const int l  = t & 63;
  const int fb = t >> 6;        // 0..3
  const int rm = l & 15;
  const int kg = l >> 4;        // 0..3
  const int kcol = kt * 32 + kg * 8;
  uint16_t* dst = wsW + (size_t)kt * (C_L1 * 32) + (size_t)l * 8;
#pragma unroll
  for (int q = 0; q < 4; ++q) {
    const int f = fb * 4 + q;
    const int row = f * 16 + rm;
    const float4* s = (const float4*)(W + (size_t)row * C_INPUTS + kcol);
    *(short8*)(dst + (size_t)f * 512) = pack_bf16x8(s[0], s[1]);
  }
}

// ---------------------------------------------------------------------------
// Kernel 2: GEMM — BARRIER-FREE. Block = (mb, ks): 64 rows x 256 cols,
// BK=32, NITER=160 (KSPLIT=8). 4 independent waves; wave w owns col-quadrant
// [64w, 64w+64) (frags 4w..4w+3). NO LDS, NO __syncthreads, NO inline asm:
// - A: per-lane DIRECT global->VGPR fragment loads (lane l reads rows
//   {0,16,32,48}+(l&15), 8 consecutive f32 at k-group (l>>4)*8). The 4 waves
//   read identical A addresses -> L1/L2 absorb the redundancy; HBM sees A once.
//   f32 sets double-buffered at distance 2 (~2 iters ~= 3000 cyc >> 900 HBM).
// - W: L2-resident fragment-major workspace -> VGPR, distance 1 (>= 1500 cyc
//   cover vs ~300 L2 latency). ks = bid%8 is XCD-affine: each XCD's L2 holds
//   exactly its 2.6MB W chunk.
// Only register-dependency s_waitcnt remains; compiler schedules freely.
// ---------------------------------------------------------------------------
template<int KSPLIT>
__global__ __launch_bounds__(256, 2) void k_gemm(const float* __restrict__ w_in,
                                                 const float* __restrict__ b_in,
                                                 const uint16_t* __restrict__ wsW,
                                                 float* __restrict__ wsP) {
  constexpr int KCHUNK = C_KEFF / KSPLIT;   // 5120
  constexpr int NITER  = KCHUNK / 32;       // 160, even

  const int bid  = blockIdx.x;
  const int ks   = bid % KSPLIT;
  const int mb   = bid / KSPLIT;  // 0..63
  const int tid  = threadIdx.x;
  const int wave = tid >> 6;
  const int lane = tid & 63;
  const int lrow = lane & 15;
  const int lg   = lane >> 4;

  const float* Abase = (mb < 32) ? (w_in + (size_t)mb * 64 * C_INPUTS)
                                 : (b_in + (size_t)(mb - 32) * 64 * C_INPUTS);
  // Per-lane A fragment source: row lrow (+16*mi), 8 consecutive f32 at lg*8.
  const float* arow = Abase + (size_t)lrow * C_INPUTS + ks * KCHUNK + lg * 8;
  // W fragment source: frag f = wave*4 + nj at elem offsets {0,512,1024,1536}.
  const uint16_t* wptr = wsW + (size_t)(ks * NITER) * 8192
                       + wave * 2048 + lane * 8;

  f32x4 acc[4][4];
#pragma unroll
  for (int i = 0; i < 4; ++i)
#pragma unroll
    for (int j = 0; j < 4; ++j) acc[i][j] = (f32x4){0.f, 0.f, 0.f, 0.f};

  float4 sA[8], sB[8];     // two A f32 sets: 4 rows x 2 float4 each
  short8 af[4];            // current A bf16 fragments
  short8 wA[4], wB[4];     // W double buffer

#define LOAD_A(DST, T) do {                                                  \
    _Pragma("unroll") for (int mi_ = 0; mi_ < 4; ++mi_) {                    \
      const float4* p_ = (const float4*)(arow + (size_t)mi_ * 16 * C_INPUTS  \
                                         + (size_t)(T) * 32);                \
      DST[2 * mi_]     = p_[0];                                              \
      DST[2 * mi_ + 1] = p_[1];                                              \
    }                                                                        \
  } while (0)

#define LOAD_W(DST, TILE) do {                                               \
    const uint16_t* q_ = wptr + (size_t)(TILE) * 8192;                       \
    DST[0] = *(const short8*)(q_);                                           \
    DST[1] = *(const short8*)(q_ + 512);                                     \
    DST[2] = *(const short8*)(q_ + 1024);                                    \
    DST[3] = *(const short8*)(q_ + 1536);                                    \
  } while (0)

#define CVT_A(SRC) do {                                                      \
    _Pragma("unroll") for (int mi_ = 0; mi_ < 4; ++mi_)                      \
      af[mi_] = pack_bf16x8(SRC[2 * mi_], SRC[2 * mi_ + 1]);                 \
  } while (0)

  // ---- prologue ----
  LOAD_A(sA, 0);
  LOAD_A(sB, 1);
  LOAD_W(wA, 0);
  CVT_A(sA);               // af = A(0); sA now free

  // STEP(T): issue A(T+2)->SI and W(T+1)->WN; MFMA(af=A(T), WC);
  // then convert SC (=A(T+1), issued at T-1, ~2 iters old) -> af.
#define STEP(T, WC, WN, SI, SC) do {                                          \
    if ((T) + 2 < NITER) LOAD_A(SI, (T) + 2);                                 \
    if ((T) + 1 < NITER) LOAD_W(WN, (T) + 1);                                 \
    _Pragma("unroll") for (int mi_ = 0; mi_ < 4; ++mi_)                       \
      _Pragma("unroll") for (int nj_ = 0; nj_ < 4; ++nj_)                     \
        acc[mi_][nj_] = __builtin_amdgcn_mfma_f32_16x16x32_bf16(              \
            af[mi_], WC[nj_], acc[mi_][nj_], 0, 0, 0);                        \
    if ((T) + 1 < NITER) CVT_A(SC);                                           \
  } while (0)

#pragma unroll 1
  for (int t = 0; t < NITER; t += 2) {
    STEP(t,     wA, wB, sA, sB);   // A(t+2)->sA, W(t+1)->wB, cvt A(t+1)=sB
    STEP(t + 1, wB, wA, sB, sA);   // A(t+3)->sB, W(t+2)->wA, cvt A(t+2)=sA
  }
#undef STEP
#undef LOAD_A
#undef LOAD_W
#undef CVT_A

  // ---- store partials: C/D layout col=lane&15, row=(lane>>4)*4+reg ----
  float* P = wsP + ((size_t)ks * 4096 + (size_t)mb * 64) * 256;
#pragma unroll
  for (int mi = 0; mi < 4; ++mi)
#pragma unroll
    for (int nj = 0; nj < 4; ++nj)
#pragma unroll
      for (int j = 0; j < 4; ++j) {
        const int rr = mi * 16 + lg * 4 + j;
        const int cc = wave * 64 + nj * 16 + lrow;
        P[(size_t)rr * 256 + cc] = acc[mi][nj][j];
      }
}

// ---------------------------------------------------------------------------
// Kernel 3: reduce KSPLIT partials, add bias, perspective mix, clamp.
// ---------------------------------------------------------------------------
template<int KSPLIT>
__global__ __launch_bounds__(256) void k_reduce(const float* __restrict__ wsP,
                                                const float* __restrict__ us,
                                                const float* __restrict__ them,
                                                const float* __restrict__ bias,
                                                float* __restrict__ out) {
  const int r = blockIdx.x;    // 0..2047
  const int c = threadIdx.x;   // 0..255
  float wd = 0.f, bd = 0.f;
#pragma unroll
  for (int s = 0; s < KSPLIT; ++s) {
    wd += wsP[((size_t)s * 4096 + r) * 256 + c];
    bd += wsP[((size_t)s * 4096 + 2048 + r) * 256 + c];
  }
  const float bi = bias[c];
  const float w = wd + bi;
  const float b = bd + bi;
  const float u = us[r];
  const float t = them[r];
  float o1 = u * w + t * b;
  float o2 = u * b + t * w;
  o1 = fminf(fmaxf(o1, 0.f), 1.f);
  o2 = fminf(fmaxf(o2, 0.f), 1.f);
  out[(size_t)r * 512 + c]       = o1;
  out[(size_t)r * 512 + 256 + c] = o2;
}

extern "C" void kernel_launch(void* const* d_in, const int* in_sizes, int n_in,
                              void* d_out, int out_size, void* d_ws, size_t ws_size,
                              hipStream_t stream) {
  const float* us   = (const float*)d_in[0];
  const float* them = (const float*)d_in[1];
  const float* w_in = (const float*)d_in[2];
  const float* b_in = (const float*)d_in[3];
  const float* W    = (const float*)d_in[4];
  const float* bias = (const float*)d_in[5];
  float* out = (float*)d_out;

  uint16_t* wsW = (uint16_t*)d_ws;
  float*    wsP = (float*)((char*)d_ws + WS_W_BYTES);

  k_convert_w<<<C_NT32, 256, 0, stream>>>(W, wsW);
  k_gemm<8><<<64 * 8, 256, 0, stream>>>(w_in, b_in, wsW, wsP);
  k_reduce<8><<<2048, 256, 0, stream>>>(wsP, us, them, bias, out);
}

// Round 6
// 264.739 us; speedup vs baseline: 1.4090x; 1.4090x over previous
//
#include <hip/hip_runtime.h>
#include <stdint.h>

#define C_INPUTS 41024
#define C_KEFF   40960   // last 64 cols of W are zero -> skipped exactly
#define C_L1     256
#define C_NT32   (C_KEFF / 32)                    // 1280 32-k tiles
#define WS_W_BYTES ((size_t)C_L1 * C_KEFF * 2)    // 20,971,520

#define G_WT   16384                 // W tile bytes (256 cols x 32 k, bf16)
#define G_AT   8192                  // A tile bytes (64 rows x 32 k, f32)
#define G_BUF  (G_WT + G_AT)         // 24576
#define G_LDS  (2 * G_BUF)           // 49152 -> 3 blocks/CU

typedef __attribute__((ext_vector_type(8))) short short8;
typedef __attribute__((ext_vector_type(4))) float f32x4;

typedef __attribute__((address_space(1))) const uint32_t g_as1_u32;
typedef __attribute__((address_space(3))) uint32_t      l_as3_u32;

__device__ __forceinline__ uint16_t bf16_rtne(float f) {
  uint32_t u = __builtin_bit_cast(uint32_t, f);
  u += 0x7fffu + ((u >> 16) & 1u);
  return (uint16_t)(u >> 16);
}

__device__ __forceinline__ short8 pack_bf16x8(float4 a, float4 b) {
  union { uint16_t h[8]; short8 v; } u;
  u.h[0] = bf16_rtne(a.x); u.h[1] = bf16_rtne(a.y);
  u.h[2] = bf16_rtne(a.z); u.h[3] = bf16_rtne(a.w);
  u.h[4] = bf16_rtne(b.x); u.h[5] = bf16_rtne(b.y);
  u.h[6] = bf16_rtne(b.z); u.h[7] = bf16_rtne(b.w);
  return u.v;
}

// ---------------------------------------------------------------------------
// Kernel 1: W [256, 41024] f32 -> bf16 workspace in FRAGMENT-MAJOR 32-k tiles.
// Tile kt (16 KB): frag f (cols 16f..16f+15) at byte f*1024; elem (f, l, j) =
// W[16f + (l&15)][kt*32 + (l>>4)*8 + j] at byte f*1024 + l*16.
// The GEMM stages each tile with linear global_load_lds and ds_reads frags at
// lane*16 -> conflict-free by construction.
// ---------------------------------------------------------------------------
__global__ __launch_bounds__(256) void k_convert_w(const float* __restrict__ W,
                                                   uint16_t* __restrict__ wsW) {
  const int kt = blockIdx.x;    // 0..1279
  const int t  = threadIdx.x;
  const int l  = t & 63;
  const int fb = t >> 6;        // 0..3
  const int rm = l & 15;
  const int kg = l >> 4;        // 0..3
  const int kcol = kt * 32 + kg * 8;
  uint16_t* dst = wsW + (size_t)kt * (C_L1 * 32) + (size_t)l * 8;
#pragma unroll
  for (int q = 0; q < 4; ++q) {
    const int f = fb * 4 + q;
    const int row = f * 16 + rm;
    const float4* s = (const float4*)(W + (size_t)row * C_INPUTS + kcol);
    *(short8*)(dst + (size_t)f * 512) = pack_bf16x8(s[0], s[1]);
  }
}

// ---------------------------------------------------------------------------
// Kernel 2: GEMM, all-global_load_lds (zero register staging -> compiler
// can't serialize the prefetch). Block = (mb, ks): 64 rows x 256 cols, BK=32.
// Per 24KB buffer: W bf16 16KB (fragment-major, linear copy from wsW) +
// A f32 8KB row-major [64][32] with XOR swizzle g^=(row&7) applied on the
// GLOBAL source (LDS dest linear, rule #21):
//   A LDS byte(row, g) = G_WT + row*128 + (g ^ (row&7))*16   (g = 16B k-group)
// Staging: issue c in {0,1}: thread t -> LDS byte c*4096+t*16, source row
// c*32+(t>>3), k-group (t&7)^(row&7) -> 8 lanes cover one full 128B row.
// Reads: af[mi] from rows mi*16+lrow, groups (2lg)^(lrow&7), (2lg+1)^(lrow&7)
// -> all bank-quads uniformly covered. f32->bf16 pack happens at read time.
// Double-buffered, one __syncthreads per iter; 3 blocks/CU overlap the
// barrier vmcnt drains (m97/m114 mechanism).
// ---------------------------------------------------------------------------
template<int KSPLIT>
__global__ __launch_bounds__(256, 3) void k_gemm(const float* __restrict__ w_in,
                                                 const float* __restrict__ b_in,
                                                 const uint16_t* __restrict__ wsW,
                                                 float* __restrict__ wsP) {
  constexpr int KCHUNK = C_KEFF / KSPLIT;   // 2560 (KSPLIT=16)
  constexpr int NITER  = KCHUNK / 32;       // 80
  extern __shared__ char smem[];

  const int bid  = blockIdx.x;
  const int ks   = bid % KSPLIT;
  const int mb   = bid / KSPLIT;  // 0..63
  const int tid  = threadIdx.x;
  const int wave = tid >> 6;
  const int lane = tid & 63;
  const int lrow = lane & 15;
  const int lg   = lane >> 4;

  const float* Abase = (mb < 32) ? (w_in + (size_t)mb * 64 * C_INPUTS)
                                 : (b_in + (size_t)(mb - 32) * 64 * C_INPUTS);

  // A staging sources (per-lane, pre-swizzled k-group):
  const int arow = tid >> 3;                       // 0..31
  const int ag   = (tid & 7) ^ (arow & 7);         // swizzled 16B k-group
  const char* aSrc0 = (const char*)(Abase + (size_t)arow * C_INPUTS
                                    + ks * KCHUNK + ag * 4);
  const char* aSrc1 = (const char*)(Abase + (size_t)(arow + 32) * C_INPUTS
                                    + ks * KCHUNK + ag * 4);
  // W staging source: byte-linear copy of the 16KB tile.
  const char* wSrc = (const char*)wsW + (size_t)(ks * NITER) * G_WT
                   + (size_t)tid * 16;

  // LDS read constants
  const int g1 = (2 * lg)     ^ (lrow & 7);
  const int g2 = (2 * lg + 1) ^ (lrow & 7);

  f32x4 acc[4][4];
#pragma unroll
  for (int i = 0; i < 4; ++i)
#pragma unroll
    for (int j = 0; j < 4; ++j) acc[i][j] = (f32x4){0.f, 0.f, 0.f, 0.f};

#define PREFETCH(TT, NB) do {                                                  \
    const char* ws_ = wSrc + (size_t)(TT) * G_WT;                              \
    _Pragma("unroll")                                                          \
    for (int c = 0; c < 4; ++c)                                                \
      __builtin_amdgcn_global_load_lds(                                        \
          (g_as1_u32*)(ws_ + c * 4096),                                        \
          (l_as3_u32*)(smem + (NB) + c * 4096 + tid * 16), 16, 0, 0);          \
    __builtin_amdgcn_global_load_lds(                                          \
        (g_as1_u32*)(aSrc0 + (size_t)(TT) * 128),                              \
        (l_as3_u32*)(smem + (NB) + G_WT + tid * 16), 16, 0, 0);                \
    __builtin_amdgcn_global_load_lds(                                          \
        (g_as1_u32*)(aSrc1 + (size_t)(TT) * 128),                              \
        (l_as3_u32*)(smem + (NB) + G_WT + 4096 + tid * 16), 16, 0, 0);         \
  } while (0)

  // ---- prologue: tile 0 -> buffer 0 ----
  PREFETCH(0, 0);
  __syncthreads();

#pragma unroll 1
  for (int T = 0; T < NITER; ++T) {
    if (T + 1 < NITER) PREFETCH(T + 1, ((T + 1) & 1) * G_BUF);

    const char* cb = smem + (T & 1) * G_BUF;
    short8 wf[4], af[4];
#pragma unroll
    for (int nj = 0; nj < 4; ++nj)
      wf[nj] = *(const short8*)(cb + (wave * 4 + nj) * 1024 + lane * 16);
#pragma unroll
    for (int mi = 0; mi < 4; ++mi) {
      const char* ar = cb + G_WT + (mi * 16 + lrow) * 128;
      float4 a0 = *(const float4*)(ar + g1 * 16);
      float4 a1 = *(const float4*)(ar + g2 * 16);
      af[mi] = pack_bf16x8(a0, a1);
    }
#pragma unroll
    for (int mi = 0; mi < 4; ++mi)
#pragma unroll
      for (int nj = 0; nj < 4; ++nj)
        acc[mi][nj] = __builtin_amdgcn_mfma_f32_16x16x32_bf16(
            af[mi], wf[nj], acc[mi][nj], 0, 0, 0);

    __syncthreads();
  }
#undef PREFETCH

  // ---- store partials: C/D layout col=lane&15, row=(lane>>4)*4+reg ----
  float* P = wsP + ((size_t)ks * 4096 + (size_t)mb * 64) * 256;
#pragma unroll
  for (int mi = 0; mi < 4; ++mi)
#pragma unroll
    for (int nj = 0; nj < 4; ++nj)
#pragma unroll
      for (int j = 0; j < 4; ++j) {
        const int rr = mi * 16 + lg * 4 + j;
        const int cc = wave * 64 + nj * 16 + lrow;
        P[(size_t)rr * 256 + cc] = acc[mi][nj][j];
      }
}

// ---------------------------------------------------------------------------
// Kernel 3: reduce KSPLIT partials, add bias, perspective mix, clamp.
// ---------------------------------------------------------------------------
template<int KSPLIT>
__global__ __launch_bounds__(256) void k_reduce(const float* __restrict__ wsP,
                                                const float* __restrict__ us,
                                                const float* __restrict__ them,
                                                const float* __restrict__ bias,
                                                float* __restrict__ out) {
  const int r = blockIdx.x;    // 0..2047
  const int c = threadIdx.x;   // 0..255
  float wd = 0.f, bd = 0.f;
#pragma unroll
  for (int s = 0; s < KSPLIT; ++s) {
    wd += wsP[((size_t)s * 4096 + r) * 256 + c];
    bd += wsP[((size_t)s * 4096 + 2048 + r) * 256 + c];
  }
  const float bi = bias[c];
  const float w = wd + bi;
  const float b = bd + bi;
  const float u = us[r];
  const float t = them[r];
  float o1 = u * w + t * b;
  float o2 = u * b + t * w;
  o1 = fminf(fmaxf(o1, 0.f), 1.f);
  o2 = fminf(fmaxf(o2, 0.f), 1.f);
  out[(size_t)r * 512 + c]       = o1;
  out[(size_t)r * 512 + 256 + c] = o2;
}

extern "C" void kernel_launch(void* const* d_in, const int* in_sizes, int n_in,
                              void* d_out, int out_size, void* d_ws, size_t ws_size,
                              hipStream_t stream) {
  const float* us   = (const float*)d_in[0];
  const float* them = (const float*)d_in[1];
  const float* w_in = (const float*)d_in[2];
  const float* b_in = (const float*)d_in[3];
  const float* W    = (const float*)d_in[4];
  const float* bias = (const float*)d_in[5];
  float* out = (float*)d_out;

  uint16_t* wsW = (uint16_t*)d_ws;
  float*    wsP = (float*)((char*)d_ws + WS_W_BYTES);

  k_convert_w<<<C_NT32, 256, 0, stream>>>(W, wsW);

  const size_t need16 = WS_W_BYTES + (size_t)16 * 4096 * 256 * 4;  // 88.1 MB
  if (ws_size >= need16) {
    k_gemm<16><<<64 * 16, 256, G_LDS, stream>>>(w_in, b_in, wsW, wsP);
    k_reduce<16><<<2048, 256, 0, stream>>>(wsP, us, them, bias, out);
  } else {
    k_gemm<8><<<64 * 8, 256, G_LDS, stream>>>(w_in, b_in, wsW, wsP);
    k_reduce<8><<<2048, 256, 0, stream>>>(wsP, us, them, bias, out);
  }
}

// Round 7
// 239.514 us; speedup vs baseline: 1.5574x; 1.1053x over previous
//
#include <hip/hip_runtime.h>
#include <stdint.h>

#define C_INPUTS 41024
#define C_KEFF   40960   // last 64 cols of W are zero -> skipped exactly
#define C_L1     256
#define C_NT32   (C_KEFF / 32)                    // 1280 32-k tiles
#define WS_W_BYTES ((size_t)C_L1 * C_KEFF * 2)    // 20,971,520

#define G_WT   16384                 // W tile bytes (256 cols x 32 k, bf16)
#define G_AT   8192                  // A tile bytes (64 rows x 32 k, f32)
#define G_BUF  (G_WT + G_AT)         // 24576
#define G_NBUF 3
#define G_LDS  (G_NBUF * G_BUF)      // 73728 -> 2 blocks/CU

typedef __attribute__((ext_vector_type(8))) short short8;
typedef __attribute__((ext_vector_type(4))) float f32x4;

typedef __attribute__((address_space(1))) const uint32_t g_as1_u32;
typedef __attribute__((address_space(3))) uint32_t      l_as3_u32;

__device__ __forceinline__ uint16_t bf16_rtne(float f) {
  uint32_t u = __builtin_bit_cast(uint32_t, f);
  u += 0x7fffu + ((u >> 16) & 1u);
  return (uint16_t)(u >> 16);
}

__device__ __forceinline__ short8 pack_bf16x8(float4 a, float4 b) {
  union { uint16_t h[8]; short8 v; } u;
  u.h[0] = bf16_rtne(a.x); u.h[1] = bf16_rtne(a.y);
  u.h[2] = bf16_rtne(a.z); u.h[3] = bf16_rtne(a.w);
  u.h[4] = bf16_rtne(b.x); u.h[5] = bf16_rtne(b.y);
  u.h[6] = bf16_rtne(b.z); u.h[7] = bf16_rtne(b.w);
  return u.v;
}

// HW RTNE f32x2 -> packed bf16x2 (same rounding as bf16_rtne; 1 VALU instr).
__device__ __forceinline__ uint32_t cvt_pk_bf16(float lo, float hi) {
  uint32_t r;
  asm("v_cvt_pk_bf16_f32 %0, %1, %2" : "=v"(r) : "v"(lo), "v"(hi));
  return r;
}

__device__ __forceinline__ short8 pack_bf16x8_hw(float4 a, float4 b) {
  union { uint32_t w[4]; short8 v; } u;
  u.w[0] = cvt_pk_bf16(a.x, a.y);
  u.w[1] = cvt_pk_bf16(a.z, a.w);
  u.w[2] = cvt_pk_bf16(b.x, b.y);
  u.w[3] = cvt_pk_bf16(b.z, b.w);
  return u.v;
}

// ---------------------------------------------------------------------------
// Kernel 1: W [256, 41024] f32 -> bf16 workspace in FRAGMENT-MAJOR 32-k tiles.
// Tile kt (16 KB): frag f (cols 16f..16f+15) at byte f*1024; elem (f, l, j) =
// W[16f + (l&15)][kt*32 + (l>>4)*8 + j] at byte f*1024 + l*16.
// GEMM stages tiles with linear global_load_lds, ds_reads frags at lane*16.
// ---------------------------------------------------------------------------
__global__ __launch_bounds__(256) void k_convert_w(const float* __restrict__ W,
                                                   uint16_t* __restrict__ wsW) {
  const int kt = blockIdx.x;    // 0..1279
  const int t  = threadIdx.x;
  const int l  = t & 63;
  const int fb = t >> 6;        // 0..3
  const int rm = l & 15;
  const int kg = l >> 4;        // 0..3
  const int kcol = kt * 32 + kg * 8;
  uint16_t* dst = wsW + (size_t)kt * (C_L1 * 32) + (size_t)l * 8;
#pragma unroll
  for (int q = 0; q < 4; ++q) {
    const int f = fb * 4 + q;
    const int row = f * 16 + rm;
    const float4* s = (const float4*)(W + (size_t)row * C_INPUTS + kcol);
    *(short8*)(dst + (size_t)f * 512) = pack_bf16x8(s[0], s[1]);
  }
}

// ---------------------------------------------------------------------------
// Kernel 2: GEMM with RAW-BARRIER + COUNTED-VMCNT pipeline (T3/T4): loads
// stay in flight ACROSS barriers; vmcnt never drains to 0 in steady state.
// Block = (mb, ks): 64 rows x 256 cols, BK=32, triple-buffered 24KB tiles
// (prefetch distance 2 ~= 2 iters >> HBM latency).
// Per iter (6 global_load_lds = 4 W + 2 A):
//   s_barrier                       // all waves consumed tile T-1
//   issue prefetch T+2 -> buf (T+2)%3
//   s_waitcnt vmcnt(12)             // newest 12 = {T+1,T+2} -> T proven done
//   ds_read tile T, cvt_pk, 16 MFMA // lgkmcnt auto-inserted by compiler
// A LDS: row-major [64][128B], XOR swizzle g^=(row&7) applied on the GLOBAL
// source (dest linear, rule #21). W LDS: fragment-major, byte-linear copy.
// ---------------------------------------------------------------------------
template<int KSPLIT>
__global__ __launch_bounds__(256, 2) void k_gemm(const float* __restrict__ w_in,
                                                 const float* __restrict__ b_in,
                                                 const uint16_t* __restrict__ wsW,
                                                 float* __restrict__ wsP) {
  constexpr int KCHUNK = C_KEFF / KSPLIT;
  constexpr int NITER  = KCHUNK / 32;
  extern __shared__ char smem[];

  const int bid  = blockIdx.x;
  const int ks   = bid % KSPLIT;   // XCD-affine W chunk
  const int mb   = bid / KSPLIT;   // 0..63
  const int tid  = threadIdx.x;
  const int wave = tid >> 6;
  const int lane = tid & 63;
  const int lrow = lane & 15;
  const int lg   = lane >> 4;

  const float* Abase = (mb < 32) ? (w_in + (size_t)mb * 64 * C_INPUTS)
                                 : (b_in + (size_t)(mb - 32) * 64 * C_INPUTS);

  // A staging sources (per-lane, pre-swizzled k-group):
  const int arow = tid >> 3;                       // 0..31
  const int ag   = (tid & 7) ^ (arow & 7);         // swizzled 16B k-group
  const char* aSrc0 = (const char*)(Abase + (size_t)arow * C_INPUTS
                                    + ks * KCHUNK + ag * 4);
  const char* aSrc1 = (const char*)(Abase + (size_t)(arow + 32) * C_INPUTS
                                    + ks * KCHUNK + ag * 4);
  // W staging source: byte-linear copy of the 16KB fragment-major tile.
  const char* wSrc = (const char*)wsW + (size_t)(ks * NITER) * G_WT
                   + (size_t)tid * 16;

  // LDS read constants (A fragment groups, swizzled)
  const int g1 = (2 * lg)     ^ (lrow & 7);
  const int g2 = (2 * lg + 1) ^ (lrow & 7);

  f32x4 acc[4][4];
#pragma unroll
  for (int i = 0; i < 4; ++i)
#pragma unroll
    for (int j = 0; j < 4; ++j) acc[i][j] = (f32x4){0.f, 0.f, 0.f, 0.f};

#define PREFETCH(TT, NB) do {                                                  \
    const char* ws_ = wSrc + (size_t)(TT) * G_WT;                              \
    _Pragma("unroll")                                                          \
    for (int c = 0; c < 4; ++c)                                                \
      __builtin_amdgcn_global_load_lds(                                        \
          (g_as1_u32*)(ws_ + c * 4096),                                        \
          (l_as3_u32*)(smem + (NB) + c * 4096 + tid * 16), 16, 0, 0);          \
    __builtin_amdgcn_global_load_lds(                                          \
        (g_as1_u32*)(aSrc0 + (size_t)(TT) * 128),                              \
        (l_as3_u32*)(smem + (NB) + G_WT + tid * 16), 16, 0, 0);                \
    __builtin_amdgcn_global_load_lds(                                          \
        (g_as1_u32*)(aSrc1 + (size_t)(TT) * 128),                              \
        (l_as3_u32*)(smem + (NB) + G_WT + 4096 + tid * 16), 16, 0, 0);         \
  } while (0)

  // ---- prologue: tiles 0,1 -> buffers 0,1 (12 loads outstanding) ----
  PREFETCH(0, 0);
  PREFETCH(1, G_BUF);

  int cb = 0;   // current buffer index (T % 3)
#pragma unroll 1
  for (int T = 0; T < NITER; ++T) {
    __builtin_amdgcn_s_barrier();      // raw barrier: NO compiler vmcnt drain

    if (T + 2 < NITER) {
      int pb = cb + 2; if (pb >= G_NBUF) pb -= G_NBUF;
      PREFETCH(T + 2, pb * G_BUF);
      asm volatile("s_waitcnt vmcnt(12)" ::: "memory");   // T done; {T+1,T+2} in flight
    } else if (T + 1 < NITER) {
      asm volatile("s_waitcnt vmcnt(6)" ::: "memory");    // T done; {T+1} in flight
    } else {
      asm volatile("s_waitcnt vmcnt(0)" ::: "memory");    // last tile
    }

    const char* cbuf = smem + cb * G_BUF;
    short8 wf[4], af[4];
#pragma unroll
    for (int nj = 0; nj < 4; ++nj)
      wf[nj] = *(const short8*)(cbuf + (wave * 4 + nj) * 1024 + lane * 16);
#pragma unroll
    for (int mi = 0; mi < 4; ++mi) {
      const char* ar = cbuf + G_WT + (mi * 16 + lrow) * 128;
      float4 a0 = *(const float4*)(ar + g1 * 16);
      float4 a1 = *(const float4*)(ar + g2 * 16);
      af[mi] = pack_bf16x8_hw(a0, a1);
    }
#pragma unroll
    for (int mi = 0; mi < 4; ++mi)
#pragma unroll
      for (int nj = 0; nj < 4; ++nj)
        acc[mi][nj] = __builtin_amdgcn_mfma_f32_16x16x32_bf16(
            af[mi], wf[nj], acc[mi][nj], 0, 0, 0);

    cb = cb + 1; if (cb >= G_NBUF) cb -= G_NBUF;
  }
#undef PREFETCH

  // ---- store partials: C/D layout col=lane&15, row=(lane>>4)*4+reg ----
  float* P = wsP + ((size_t)ks * 4096 + (size_t)mb * 64) * 256;
#pragma unroll
  for (int mi = 0; mi < 4; ++mi)
#pragma unroll
    for (int nj = 0; nj < 4; ++nj)
#pragma unroll
      for (int j = 0; j < 4; ++j) {
        const int rr = mi * 16 + lg * 4 + j;
        const int cc = wave * 64 + nj * 16 + lrow;
        P[(size_t)rr * 256 + cc] = acc[mi][nj][j];
      }
}

// ---------------------------------------------------------------------------
// Kernel 3: reduce KSPLIT partials, add bias, perspective mix, clamp.
// ---------------------------------------------------------------------------
template<int KSPLIT>
__global__ __launch_bounds__(256) void k_reduce(const float* __restrict__ wsP,
                                                const float* __restrict__ us,
                                                const float* __restrict__ them,
                                                const float* __restrict__ bias,
                                                float* __restrict__ out) {
  const int r = blockIdx.x;    // 0..2047
  const int c = threadIdx.x;   // 0..255
  float wd = 0.f, bd = 0.f;
#pragma unroll
  for (int s = 0; s < KSPLIT; ++s) {
    wd += wsP[((size_t)s * 4096 + r) * 256 + c];
    bd += wsP[((size_t)s * 4096 + 2048 + r) * 256 + c];
  }
  const float bi = bias[c];
  const float w = wd + bi;
  const float b = bd + bi;
  const float u = us[r];
  const float t = them[r];
  float o1 = u * w + t * b;
  float o2 = u * b + t * w;
  o1 = fminf(fmaxf(o1, 0.f), 1.f);
  o2 = fminf(fmaxf(o2, 0.f), 1.f);
  out[(size_t)r * 512 + c]       = o1;
  out[(size_t)r * 512 + 256 + c] = o2;
}

extern "C" void kernel_launch(void* const* d_in, const int* in_sizes, int n_in,
                              void* d_out, int out_size, void* d_ws, size_t ws_size,
                              hipStream_t stream) {
  const float* us   = (const float*)d_in[0];
  const float* them = (const float*)d_in[1];
  const float* w_in = (const float*)d_in[2];
  const float* b_in = (const float*)d_in[3];
  const float* W    = (const float*)d_in[4];
  const float* bias = (const float*)d_in[5];
  float* out = (float*)d_out;

  uint16_t* wsW = (uint16_t*)d_ws;
  float*    wsP = (float*)((char*)d_ws + WS_W_BYTES);

  k_convert_w<<<C_NT32, 256, 0, stream>>>(W, wsW);

  const size_t need16 = WS_W_BYTES + (size_t)16 * 4096 * 256 * 4;  // 88.1 MB
  if (ws_size >= need16) {
    k_gemm<16><<<64 * 16, 256, G_LDS, stream>>>(w_in, b_in, wsW, wsP);
    k_reduce<16><<<2048, 256, 0, stream>>>(wsP, us, them, bias, out);
  } else {
    k_gemm<8><<<64 * 8, 256, G_LDS, stream>>>(w_in, b_in, wsW, wsP);
    k_reduce<8><<<2048, 256, 0, stream>>>(wsP, us, them, bias, out);
  }
}

// Round 8
// 224.778 us; speedup vs baseline: 1.6595x; 1.0656x over previous
//
#include <hip/hip_runtime.h>
#include <stdint.h>

#define C_INPUTS 41024
#define C_KEFF   40960   // last 64 cols of W are zero -> skipped exactly
#define C_L1     256
#define C_NT32   (C_KEFF / 32)                    // 1280 32-k tiles
#define WS_W_BYTES ((size_t)C_L1 * C_KEFF * 2)    // 20,971,520

typedef __attribute__((ext_vector_type(8))) short short8;
typedef __attribute__((ext_vector_type(4))) float f32x4;

__device__ __forceinline__ uint16_t bf16_rtne(float f) {
  uint32_t u = __builtin_bit_cast(uint32_t, f);
  u += 0x7fffu + ((u >> 16) & 1u);
  return (uint16_t)(u >> 16);
}

__device__ __forceinline__ short8 pack_bf16x8(float4 a, float4 b) {
  union { uint16_t h[8]; short8 v; } u;
  u.h[0] = bf16_rtne(a.x); u.h[1] = bf16_rtne(a.y);
  u.h[2] = bf16_rtne(a.z); u.h[3] = bf16_rtne(a.w);
  u.h[4] = bf16_rtne(b.x); u.h[5] = bf16_rtne(b.y);
  u.h[6] = bf16_rtne(b.z); u.h[7] = bf16_rtne(b.w);
  return u.v;
}

// HW RTNE f32x2 -> packed bf16x2 (identical rounding to bf16_rtne).
__device__ __forceinline__ uint32_t cvt_pk_bf16(float lo, float hi) {
  uint32_t r;
  asm("v_cvt_pk_bf16_f32 %0, %1, %2" : "=v"(r) : "v"(lo), "v"(hi));
  return r;
}
__device__ __forceinline__ short8 pack_bf16x8_hw(float4 a, float4 b) {
  union { uint32_t w[4]; short8 v; } u;
  u.w[0] = cvt_pk_bf16(a.x, a.y);
  u.w[1] = cvt_pk_bf16(a.z, a.w);
  u.w[2] = cvt_pk_bf16(b.x, b.y);
  u.w[3] = cvt_pk_bf16(b.z, b.w);
  return u.v;
}

// Pinned-order global loads (volatile asm -> compiler can't reorder or
// serialize them; vmcnt accounting is deterministic, done by hand).
__device__ __forceinline__ float4 gload_f32x4(const float* p) {
  float4 r;
  asm volatile("global_load_dwordx4 %0, %1, off" : "=v"(r) : "v"(p));
  return r;
}
__device__ __forceinline__ short8 gload_bf16x8(const uint16_t* p) {
  short8 r;
  asm volatile("global_load_dwordx4 %0, %1, off" : "=v"(r) : "v"(p));
  return r;
}

// ---------------------------------------------------------------------------
// Kernel 1: W [256, 41024] f32 -> bf16 workspace in FRAGMENT-MAJOR 32-k tiles.
// Tile kt: elem(kt, f, l, j) = W[16f + (l&15)][kt*32 + (l>>4)*8 + j]
// (f = 16-col frag 0..15, l = frag lane, j = 0..7). The GEMM loads each
// fragment as one contiguous 1KB wave read straight into VGPRs.
// ---------------------------------------------------------------------------
__global__ __launch_bounds__(256) void k_convert_w(const float* __restrict__ W,
                                                   uint16_t* __restrict__ wsW) {
  const int kt = blockIdx.x;    // 0..1279
  const int t  = threadIdx.x;
  const int l  = t & 63;
  const int fb = t >> 6;        // 0..3
  const int rm = l & 15;
  const int kg = l >> 4;        // 0..3
  const int kcol = kt * 32 + kg * 8;
  uint16_t* dst = wsW + (size_t)kt * (C_L1 * 32) + (size_t)l * 8;
#pragma unroll
  for (int q = 0; q < 4; ++q) {
    const int f = fb * 4 + q;
    const int row = f * 16 + rm;
    const float4* s = (const float4*)(W + (size_t)row * C_INPUTS + kcol);
    *(short8*)(dst + (size_t)f * 512) = pack_bf16x8(s[0], s[1]);
  }
}

// ---------------------------------------------------------------------------
// Kernel 2: GEMM, BK=64, W-IN-REGISTERS (never touches LDS), A via tiny bf16
// LDS tile. Block = (mb, ks): 64 rows x 256 cols; 4 waves N-split (wave w owns
// frags 4w..4w+3); 32 MFMA per iter per wave.
// vmcnt ledger (12 asm loads per iter: A(T+1) 4 then W(T+1) 8):
//   top of T: issue 12 -> outstanding = W(T)8 + 12 -> vmcnt(12): W(T) ready.
//   post-MFMA: outstanding = A(T+1)4 + W(T+1)8 -> vmcnt(8): A(T+1) ready ->
//   cvt_pk -> ds_write -> lgkmcnt(0) -> raw s_barrier (NO vmcnt drain:
//   W(T+1) stays in flight across the barrier).
// sched_barrier(0) after each wait (rule #18: MFMAs/cvt are register-only
// consumers of asm-load outputs; "memory" clobber alone doesn't order them).
// A LDS [buf][kk*4+mi][lane]: ds_write covers each bank exactly 8 slots
// (optimal), ds_read is lane-linear (optimal). LDS total = 16 KB.
// ---------------------------------------------------------------------------
template<int KSPLIT>
__global__ __launch_bounds__(256, 2) void k_gemm(const float* __restrict__ w_in,
                                                 const float* __restrict__ b_in,
                                                 const uint16_t* __restrict__ wsW,
                                                 float* __restrict__ wsP) {
  constexpr int KCHUNK = C_KEFF / KSPLIT;   // 5120 (KSPLIT=8)
  constexpr int NITER  = KCHUNK / 64;       // 80, even
  __shared__ short8 abuf[2][512];           // [buf][(kk*4+mi)*64 + lane], 16 KB

  const int bid  = blockIdx.x;
  const int ks   = bid % KSPLIT;   // XCD-affine W chunk
  const int mb   = bid / KSPLIT;   // 0..63
  const int tid  = threadIdx.x;
  const int wave = tid >> 6;
  const int lane = tid & 63;
  const int lrow = lane & 15;
  const int lg   = lane >> 4;

  const float* Abase = (mb < 32) ? (w_in + (size_t)mb * 64 * C_INPUTS)
                                 : (b_in + (size_t)(mb - 32) * 64 * C_INPUTS);
  // A staging: thread t owns row ar = t>>2, k-quarter aq = t&3 (16 f32,
  // 64B contiguous; 4 threads cover a 256B row segment -> coalesced).
  const int ar = tid >> 2;
  const int aq = tid & 3;
  const float* aptr = Abase + (size_t)ar * C_INPUTS + ks * KCHUNK + aq * 16;
  // ds_write slots for the two bf16x8 this thread produces (g = 2aq, 2aq+1):
  const int wi0 = ((aq >> 1) * 4 + (ar >> 4)) * 64 + ((2 * aq) & 3) * 16 + (ar & 15);
  const int wi1 = ((aq >> 1) * 4 + (ar >> 4)) * 64 + ((2 * aq + 1) & 3) * 16 + (ar & 15);

  // W fragment source: frag (T, kk, nj) at wbase + (2T+kk)*8192 + nj*512 elems.
  const uint16_t* wbase = wsW + (size_t)(ks * (KCHUNK / 32)) * 8192
                        + wave * 2048 + lane * 8;

  f32x4 acc[4][4];
#pragma unroll
  for (int i = 0; i < 4; ++i)
#pragma unroll
    for (int j = 0; j < 4; ++j) acc[i][j] = (f32x4){0.f, 0.f, 0.f, 0.f};

  float4 a0, a1, a2, a3;     // in-flight A f32 (one tile)
  short8 wA[8], wB[8];       // W double buffer (8 frags per 64-k tile)

#define LOAD_A(T) do {                                                        \
    const float* p_ = aptr + (size_t)(T) * 64;                                \
    a0 = gload_f32x4(p_);      a1 = gload_f32x4(p_ + 4);                      \
    a2 = gload_f32x4(p_ + 8);  a3 = gload_f32x4(p_ + 12);                     \
  } while (0)

#define LOAD_W(DST, T) do {                                                   \
    const uint16_t* q_ = wbase + (size_t)(2 * (T)) * 8192;                    \
    DST[0] = gload_bf16x8(q_);        DST[1] = gload_bf16x8(q_ + 512);        \
    DST[2] = gload_bf16x8(q_ + 1024); DST[3] = gload_bf16x8(q_ + 1536);       \
    DST[4] = gload_bf16x8(q_ + 8192); DST[5] = gload_bf16x8(q_ + 8704);       \
    DST[6] = gload_bf16x8(q_ + 9216); DST[7] = gload_bf16x8(q_ + 9728);       \
  } while (0)

  // ---- prologue: A(0), W(0); cvt+write A(0); barrier. W(0) stays in flight.
  LOAD_A(0);
  LOAD_W(wA, 0);
  asm volatile("s_waitcnt vmcnt(8)" ::: "memory");   // A(0) done
  __builtin_amdgcn_sched_barrier(0);
  abuf[0][wi0] = pack_bf16x8_hw(a0, a1);
  abuf[0][wi1] = pack_bf16x8_hw(a2, a3);
  asm volatile("s_waitcnt lgkmcnt(0)" ::: "memory");
  __builtin_amdgcn_s_barrier();

#define STEP(T, WC, WN) do {                                                  \
    if ((T) + 1 < NITER) {                                                    \
      LOAD_A((T) + 1);                                                        \
      LOAD_W(WN, (T) + 1);                                                    \
      asm volatile("s_waitcnt vmcnt(12)" ::: "memory");  /* W(T) ready */     \
    } else {                                                                  \
      asm volatile("s_waitcnt vmcnt(0)" ::: "memory");                        \
    }                                                                         \
    __builtin_amdgcn_sched_barrier(0);                                        \
    {                                                                         \
      const int buf_ = (T) & 1;                                               \
      _Pragma("unroll")                                                       \
      for (int kk = 0; kk < 2; ++kk) {                                        \
        short8 af_[4];                                                        \
        _Pragma("unroll")                                                     \
        for (int mi = 0; mi < 4; ++mi)                                        \
          af_[mi] = abuf[buf_][(kk * 4 + mi) * 64 + lane];                    \
        _Pragma("unroll")                                                     \
        for (int mi = 0; mi < 4; ++mi)                                        \
          _Pragma("unroll")                                                   \
          for (int nj = 0; nj < 4; ++nj)                                      \
            acc[mi][nj] = __builtin_amdgcn_mfma_f32_16x16x32_bf16(            \
                af_[mi], WC[kk * 4 + nj], acc[mi][nj], 0, 0, 0);              \
      }                                                                       \
    }                                                                         \
    if ((T) + 1 < NITER) {                                                    \
      asm volatile("s_waitcnt vmcnt(8)" ::: "memory");   /* A(T+1) ready */   \
      __builtin_amdgcn_sched_barrier(0);                                      \
      const int nb_ = ((T) + 1) & 1;                                          \
      abuf[nb_][wi0] = pack_bf16x8_hw(a0, a1);                                \
      abuf[nb_][wi1] = pack_bf16x8_hw(a2, a3);                                \
      asm volatile("s_waitcnt lgkmcnt(0)" ::: "memory");                      \
      __builtin_amdgcn_s_barrier();                      /* raw: no vm drain */ \
    }                                                                         \
  } while (0)

#pragma unroll 1
  for (int t = 0; t < NITER; t += 2) {
    STEP(t,     wA, wB);
    STEP(t + 1, wB, wA);
  }
#undef STEP
#undef LOAD_A
#undef LOAD_W

  // ---- store partials: C/D layout col=lane&15, row=(lane>>4)*4+reg ----
  float* P = wsP + ((size_t)ks * 4096 + (size_t)mb * 64) * 256;
#pragma unroll
  for (int mi = 0; mi < 4; ++mi)
#pragma unroll
    for (int nj = 0; nj < 4; ++nj)
#pragma unroll
      for (int j = 0; j < 4; ++j) {
        const int rr = mi * 16 + lg * 4 + j;
        const int cc = wave * 64 + nj * 16 + lrow;
        P[(size_t)rr * 256 + cc] = acc[mi][nj][j];
      }
}

// ---------------------------------------------------------------------------
// Kernel 3: reduce KSPLIT partials, add bias, perspective mix, clamp.
// ---------------------------------------------------------------------------
template<int KSPLIT>
__global__ __launch_bounds__(256) void k_reduce(const float* __restrict__ wsP,
                                                const float* __restrict__ us,
                                                const float* __restrict__ them,
                                                const float* __restrict__ bias,
                                                float* __restrict__ out) {
  const int r = blockIdx.x;    // 0..2047
  const int c = threadIdx.x;   // 0..255
  float wd = 0.f, bd = 0.f;
#pragma unroll
  for (int s = 0; s < KSPLIT; ++s) {
    wd += wsP[((size_t)s * 4096 + r) * 256 + c];
    bd += wsP[((size_t)s * 4096 + 2048 + r) * 256 + c];
  }
  const float bi = bias[c];
  const float w = wd + bi;
  const float b = bd + bi;
  const float u = us[r];
  const float t = them[r];
  float o1 = u * w + t * b;
  float o2 = u * b + t * w;
  o1 = fminf(fmaxf(o1, 0.f), 1.f);
  o2 = fminf(fmaxf(o2, 0.f), 1.f);
  out[(size_t)r * 512 + c]       = o1;
  out[(size_t)r * 512 + 256 + c] = o2;
}

extern "C" void kernel_launch(void* const* d_in, const int* in_sizes, int n_in,
                              void* d_out, int out_size, void* d_ws, size_t ws_size,
                              hipStream_t stream) {
  const float* us   = (const float*)d_in[0];
  const float* them = (const float*)d_in[1];
  const float* w_in = (const float*)d_in[2];
  const float* b_in = (const float*)d_in[3];
  const float* W    = (const float*)d_in[4];
  const float* bias = (const float*)d_in[5];
  float* out = (float*)d_out;

  uint16_t* wsW = (uint16_t*)d_ws;
  float*    wsP = (float*)((char*)d_ws + WS_W_BYTES);

  k_convert_w<<<C_NT32, 256, 0, stream>>>(W, wsW);

  const size_t need16 = WS_W_BYTES + (size_t)16 * 4096 * 256 * 4;  // 88.1 MB
  if (ws_size >= need16) {
    k_gemm<16><<<64 * 16, 256, 0, stream>>>(w_in, b_in, wsW, wsP);
    k_reduce<16><<<2048, 256, 0, stream>>>(wsP, us, them, bias, out);
  } else {
    k_gemm<8><<<64 * 8, 256, 0, stream>>>(w_in, b_in, wsW, wsP);
    k_reduce<8><<<2048, 256, 0, stream>>>(wsP, us, them, bias, out);
  }
}